// Round 10
// baseline (892.229 us; speedup 1.0000x reference)
//
#include <hip/hip_runtime.h>
#include <stdint.h>

#define NB 8
#define NN 4096
#define NP 1024
#define NSAMP 32
#define CIN 64
#define C3 128
#define XS 20
#define SENT_DONE 0x00C0FFEEu
#define GRID1 8

typedef float v2f __attribute__((ext_vector_type(2)));

__device__ __forceinline__ float lo2f(unsigned int u) { return __uint_as_float(u << 16); }
__device__ __forceinline__ float hi2f(unsigned int u) { return __uint_as_float(u & 0xffff0000u); }
__device__ __forceinline__ unsigned short f2b(float f) {
  unsigned int u = __float_as_uint(f);
  unsigned int r = u + 0x7fffu + ((u >> 16) & 1u);
  return (unsigned short)(r >> 16);
}
__device__ __forceinline__ unsigned int packbf(float a, float b) {
  return (unsigned int)f2b(a) | ((unsigned int)f2b(b) << 16);
}

#define FMAXD(v, ctrl)                                                     \
  do {                                                                     \
    int _x = __float_as_int(v);                                            \
    int _m = __builtin_amdgcn_update_dpp(_x, _x, (ctrl), 0xf, 0xf, false); \
    (v) = fmaxf((v), __int_as_float(_m));                                  \
  } while (0)

// ---- Kernel 1: FPS ---------------------------------------------------------
// Waves 0-3: FPS at setprio(3); waves 4-15: co-resident pk-FMA ballast at
// setprio(0) -> per-CU DVFS boost (R19/R20 wins; per-CU issue-busy ~91%).
// R22: publish trim — lane wl (winner, wave-uniform from ballot+ffs) stores
// the record built from its OWN gi. Removes readlane(gi,wl) + its VALU<->SALU
// waits from the pre-store critical path. Semantics identical: wl = lowest
// lane with bestv==wmax = lowest global index (lane order == index order).
// Poll body + tail sacred (R16/R18).
__global__ __launch_bounds__(1024, 1) void fps_kernel(
    const float* __restrict__ xyz, unsigned short* __restrict__ fps_g,
    float* __restrict__ out_xyz, unsigned int* __restrict__ sent) {
#pragma clang fp contract(off)
  const int tid = threadIdx.x;
  const int b = blockIdx.x;
  const int lane = tid & 63;
  const int wv = tid >> 6;  // 0..15
  __shared__ float sx[NN], sy[NN], sz[NN];
  __shared__ __align__(16) unsigned long long slotmem[2][4];
  __shared__ unsigned short scidx[NP];
  __shared__ unsigned int sdone;
  const float* xb = xyz + (size_t)b * NN * 3;
  if (wv < 4) {
    for (int i = tid; i < NN; i += 256) {
      sx[i] = xb[3 * i + 0];
      sy[i] = xb[3 * i + 1];
      sz[i] = xb[3 * i + 2];
    }
    if (tid < 8) ((unsigned long long*)slotmem)[tid] = 0ull;  // k-field 0
    if (tid == 0) { scidx[0] = 0; sdone = 0u; }
  }
  __syncthreads();
  if (wv >= 4) {
    // ---- co-resident ballast: register-only pk-FMA, rare LDS flag check
#if __has_builtin(__builtin_amdgcn_s_setprio)
    __builtin_amdgcn_s_setprio(0);
#endif
    v2f a[8];
#pragma unroll
    for (int i = 0; i < 8; ++i) {
      float base = 1.0f + (float)(tid & 15) * 1e-6f + (float)i * 1e-7f;
      a[i] = (v2f){base, base + 1e-7f};
    }
    const v2f c1 = (v2f){1.0000001f, 1.0000001f};
    const v2f c2 = (v2f){1e-9f, 1e-9f};
    for (int r = 0; r < 400000; ++r) {
#pragma unroll
      for (int i = 0; i < 8; ++i) a[i] = a[i] * c1 + c2;
      if ((r & 63) == 0) {
        if (__hip_atomic_load(&sdone, __ATOMIC_RELAXED,
                              __HIP_MEMORY_SCOPE_WORKGROUP) != 0u)
          break;
      }
    }
    float s = 0.f;
#pragma unroll
    for (int i = 0; i < 8; ++i) s += a[i].x + a[i].y;
    asm volatile("" ::"v"(s));  // keep ballast live (rule #17)
  } else {
    // ---- FPS path
#if __has_builtin(__builtin_amdgcn_s_setprio)
    __builtin_amdgcn_s_setprio(3);
#endif
    v2f px[8], py[8], pz[8], dd[8];
#pragma unroll
    for (int i = 0; i < 8; ++i) {
      int i0 = tid * 16 + 2 * i;
      px[i] = (v2f){sx[i0], sx[i0 + 1]};
      py[i] = (v2f){sy[i0], sy[i0 + 1]};
      pz[i] = (v2f){sz[i0], sz[i0 + 1]};
      dd[i] = (v2f){1e10f, 1e10f};
    }
    float qx = sx[0], qy = sy[0], qz = sz[0];
    for (int k = 1; k < NP; ++k) {
      v2f q2x = (v2f){qx, qx};
      v2f q2y = (v2f){qy, qy};
      v2f q2z = (v2f){qz, qz};
#pragma unroll
      for (int i = 0; i < 8; ++i) {
        v2f dx = px[i] - q2x;
        v2f dy = py[i] - q2y;
        v2f dz = pz[i] - q2z;
        v2f xx = dx * dx;
        v2f yy = dy * dy;
        v2f zz = dz * dz;
        v2f s = xx + yy;
        v2f d = s + zz;  // per-element np order, contract off
        dd[i] = __builtin_elementwise_min(dd[i], d);
      }
      // intra-thread argmax over 16 (first-index ties: strict >, left=lower)
      float v1[8]; int j1[8];
#pragma unroll
      for (int i = 0; i < 8; ++i) {
        bool g = dd[i].y > dd[i].x;
        v1[i] = g ? dd[i].y : dd[i].x;
        j1[i] = 2 * i + (g ? 1 : 0);
      }
      float v2a[4]; int j2a[4];
#pragma unroll
      for (int i = 0; i < 4; ++i) {
        bool g = v1[2 * i + 1] > v1[2 * i];
        v2a[i] = g ? v1[2 * i + 1] : v1[2 * i];
        j2a[i] = g ? j1[2 * i + 1] : j1[2 * i];
      }
      float v3[2]; int j3[2];
#pragma unroll
      for (int i = 0; i < 2; ++i) {
        bool g = v2a[2 * i + 1] > v2a[2 * i];
        v3[i] = g ? v2a[2 * i + 1] : v2a[2 * i];
        j3[i] = g ? j2a[2 * i + 1] : j2a[2 * i];
      }
      bool g0 = v3[1] > v3[0];
      float bestv = g0 ? v3[1] : v3[0];
      int gi = tid * 16 + (g0 ? j3[1] : j3[0]);
      // wave max via DPP
      float m = bestv;
      FMAXD(m, 0x111); FMAXD(m, 0x112); FMAXD(m, 0x114);
      FMAXD(m, 0x118); FMAXD(m, 0x142); FMAXD(m, 0x143);
      float wmax =
          __int_as_float(__builtin_amdgcn_readlane(__float_as_int(m), 63));
      unsigned long long ball = __ballot(bestv == wmax);
      int wl = __ffsll((long long)ball) - 1;  // lowest lane == lowest index
      // R22: lane wl stores directly with its OWN gi (no readlane).
      unsigned long long rec =
          ((unsigned long long)(((unsigned)k << 12) | (unsigned)gi) << 32) |
          (unsigned long long)__float_as_uint(wmax);
      unsigned long long* sl = &slotmem[k & 1][0];
      if (lane == wl) sl[wv] = rec;
      asm volatile("" ::: "memory");
      // poll: two independent 16B loads per spin (sacred)
      unsigned long long s0, s1, s2, s3;
      for (;;) {
        ulonglong2 pa = *(const ulonglong2*)(sl);
        ulonglong2 pb = *(const ulonglong2*)(sl + 2);
        s0 = pa.x; s1 = pa.y; s2 = pb.x; s3 = pb.y;
        if ((unsigned)(s0 >> 44) == (unsigned)k &&
            (unsigned)(s1 >> 44) == (unsigned)k &&
            (unsigned)(s2 >> 44) == (unsigned)k &&
            (unsigned)(s3 >> 44) == (unsigned)k)
          break;
        asm volatile("" ::: "memory");
      }
      float bv = __uint_as_float((unsigned)s0);
      int wi = (int)((s0 >> 32) & 0xFFFu);
      {
        float v = __uint_as_float((unsigned)s1);
        int iw = (int)((s1 >> 32) & 0xFFFu);
        bool g = v > bv; bv = g ? v : bv; wi = g ? iw : wi;
      }
      {
        float v = __uint_as_float((unsigned)s2);
        int iw = (int)((s2 >> 32) & 0xFFFu);
        bool g = v > bv; bv = g ? v : bv; wi = g ? iw : wi;
      }
      {
        float v = __uint_as_float((unsigned)s3);
        int iw = (int)((s3 >> 32) & 0xFFFu);
        bool g = v > bv; bv = g ? v : bv; wi = g ? iw : wi;
      }
      qx = sx[wi]; qy = sy[wi]; qz = sz[wi];  // broadcast reads
      if (tid == 0) scidx[k] = (unsigned short)wi;
    }
    if (tid == 0)
      __hip_atomic_store(&sdone, 1u, __ATOMIC_RELAXED,
                         __HIP_MEMORY_SCOPE_WORKGROUP);
  }
  __syncthreads();
  for (int i = tid; i < NP; i += 1024) {
    int id = scidx[i];
    out_xyz[((size_t)b * NP + i) * 3 + 0] = sx[id];
    out_xyz[((size_t)b * NP + i) * 3 + 1] = sy[id];
    out_xyz[((size_t)b * NP + i) * 3 + 2] = sz[id];
    fps_g[b * NP + i] = (unsigned short)id;
  }
  __syncthreads();
  if (tid == 0)
    __hip_atomic_store(&sent[b], SENT_DONE, __ATOMIC_RELAXED,
                       __HIP_MEMORY_SCOPE_AGENT);
}

// ---- Kernel 2: ball query (one wave per center; standalone — R10) ----------
__global__ __launch_bounds__(256) void ballq_kernel(
    const float* __restrict__ xyz, const unsigned short* __restrict__ fps_idx,
    unsigned short* __restrict__ gidx) {
#pragma clang fp contract(off)
  const int tid = threadIdx.x;
  const int gid = blockIdx.x * 4 + (tid >> 6);
  const int lane = tid & 63;
  const int b = gid >> 10;
  const int s = gid & 1023;
  const float* xb = xyz + (size_t)b * NN * 3;
  const int ci = (int)fps_idx[b * NP + s] & (NN - 1);
  const float cx = xb[ci * 3 + 0];
  const float cy = xb[ci * 3 + 1];
  const float cz = xb[ci * 3 + 2];
  const float nn = (cx * cx + cy * cy) + cz * cz;
  const float r2 = 0.04f;
  unsigned short* gout = gidx + (size_t)(b * NP + s) * NSAMP;
  int total = 0;
  int first = -1;
  for (int c = 0; c < NN / 64 && total < NSAMP; ++c) {
    int i = (c << 6) + lane;
    float x = xb[i * 3 + 0];
    float y = xb[i * 3 + 1];
    float z = xb[i * 3 + 2];
    float pp = (x * x + y * y) + z * z;
    float dt = (x * cx + y * cy) + z * cz;
    float sq = (nn + pp) - 2.0f * dt;  // exact ref formula; self-dist == 0
    bool inb = !(sq > r2);
    unsigned long long m = __ballot(inb);
    if (first < 0 && m) first = (c << 6) + (__ffsll((unsigned long long)m) - 1);
    int before = __popcll(m & ((1ull << lane) - 1ull));
    int slot = total + before;
    if (inb && slot < NSAMP) gout[slot] = (unsigned short)i;
    total += (int)__popcll(m);
  }
  int cnt = total < NSAMP ? total : NSAMP;
  unsigned short fill = (unsigned short)(first < 0 ? 0 : first);
  if (lane >= cnt && lane < NSAMP) gout[lane] = fill;
}

// ---- Kernel 3: gather + MLP(67->64->64->128) + max --------------------------
// R21: v2f accumulator + elementwise_fma (v_pk_fma_f32). Measured neutral vs
// scalar (compiler SLP had it covered) — kept, bit-identical math.
__global__ __launch_bounds__(256) void mlp_kernel(
    const float* __restrict__ xyz, const float* __restrict__ points,
    const unsigned short* __restrict__ fps_idx, const unsigned short* __restrict__ gidx,
    const float* __restrict__ W0, const float* __restrict__ b0,
    const float* __restrict__ g0, const float* __restrict__ be0,
    const float* __restrict__ W1, const float* __restrict__ b1,
    const float* __restrict__ g1, const float* __restrict__ be1,
    const float* __restrict__ W2, const float* __restrict__ b2,
    const float* __restrict__ g2, const float* __restrict__ be2,
    float* __restrict__ out_feat) {
  __shared__ __align__(16) float wbuf[4352];
  __shared__ __align__(16) unsigned int xpk[8 * 68 * XS];
  __shared__ float prm[768];
  const int tid = threadIdx.x;
  const float bnsc = 1.0f / sqrtf(1.001f);
  if (tid < 64) {
    prm[tid] = b0[tid];       prm[64 + tid] = g0[tid] * bnsc;  prm[128 + tid] = be0[tid];
    prm[192 + tid] = b1[tid]; prm[256 + tid] = g1[tid] * bnsc; prm[320 + tid] = be1[tid];
  }
  if (tid < 128) {
    prm[384 + tid] = b2[tid]; prm[512 + tid] = g2[tid] * bnsc; prm[640 + tid] = be2[tid];
  }
  if (tid < 128) {
    const int cbg = tid >> 4, r2 = tid & 15;
    const int sgg = blockIdx.x * 8 + cbg;
    const int bg = sgg >> 10, sg = sgg & 1023;
    const unsigned short* gi = gidx + (size_t)(bg * NP + sg) * NSAMP;
    const int i0 = (int)gi[2 * r2] & (NN - 1);
    const int i1 = (int)gi[2 * r2 + 1] & (NN - 1);
    const int ci = (int)fps_idx[bg * NP + sg] & (NN - 1);
    const float* xb = xyz + (size_t)bg * NN * 3;
    unsigned int* xc = &xpk[(cbg * 68) * XS + r2];
    const float cx = xb[ci * 3], cy = xb[ci * 3 + 1], cz = xb[ci * 3 + 2];
    xc[0 * XS] = packbf(xb[i0 * 3] - cx,     xb[i1 * 3] - cx);
    xc[1 * XS] = packbf(xb[i0 * 3 + 1] - cy, xb[i1 * 3 + 1] - cy);
    xc[2 * XS] = packbf(xb[i0 * 3 + 2] - cz, xb[i1 * 3 + 2] - cz);
    const float4* p0 = (const float4*)(points + ((size_t)bg * NN + i0) * CIN);
    const float4* p1 = (const float4*)(points + ((size_t)bg * NN + i1) * CIN);
#pragma unroll 4
    for (int kk = 0; kk < 16; ++kk) {
      float4 a = p0[kk], c = p1[kk];
      xc[(3 + 4 * kk) * XS] = packbf(a.x, c.x);
      xc[(4 + 4 * kk) * XS] = packbf(a.y, c.y);
      xc[(5 + 4 * kk) * XS] = packbf(a.z, c.z);
      xc[(6 + 4 * kk) * XS] = packbf(a.w, c.w);
    }
  } else {
    for (int i = tid - 128; i < 67 * 64; i += 128) wbuf[i] = W0[i];
  }
  const int cb = tid >> 5, rg = (tid >> 3) & 3, cg = tid & 7;
  const int sgc = blockIdx.x * 8 + cb;
  const int bc = sgc >> 10, sc = sgc & 1023;
  const unsigned int* xrow = &xpk[(cb * 68) * XS + rg * 4];
  // acc[r*8+c] == acc2[r*4 + (c>>1)] component (c&1)
  v2f acc2[32];
  auto getacc = [&](int r, int c) -> float {
    v2f t = acc2[r * 4 + (c >> 1)];
    return (c & 1) ? t.y : t.x;
  };
  auto kloop = [&](int K) {
    uint4 xp = *(const uint4*)(xrow);
    float4 wa = *(const float4*)&wbuf[cg * 8];
    float4 wc = *(const float4*)&wbuf[cg * 8 + 4];
#pragma unroll 2
    for (int k = 0; k < K; ++k) {
      uint4 xpn = *(const uint4*)(xrow + (k + 1) * XS);
      float4 wan = *(const float4*)&wbuf[(k + 1) * 64 + cg * 8];
      float4 wcn = *(const float4*)&wbuf[(k + 1) * 64 + cg * 8 + 4];
      float xr[8] = {lo2f(xp.x), hi2f(xp.x), lo2f(xp.y), hi2f(xp.y),
                     lo2f(xp.z), hi2f(xp.z), lo2f(xp.w), hi2f(xp.w)};
      v2f w01 = (v2f){wa.x, wa.y};
      v2f w23 = (v2f){wa.z, wa.w};
      v2f w45 = (v2f){wc.x, wc.y};
      v2f w67 = (v2f){wc.z, wc.w};
#pragma unroll
      for (int r = 0; r < 8; ++r) {
        v2f xq = (v2f){xr[r], xr[r]};
        acc2[r * 4 + 0] = __builtin_elementwise_fma(xq, w01, acc2[r * 4 + 0]);
        acc2[r * 4 + 1] = __builtin_elementwise_fma(xq, w23, acc2[r * 4 + 1]);
        acc2[r * 4 + 2] = __builtin_elementwise_fma(xq, w45, acc2[r * 4 + 2]);
        acc2[r * 4 + 3] = __builtin_elementwise_fma(xq, w67, acc2[r * 4 + 3]);
      }
      xp = xpn; wa = wan; wc = wcn;
    }
  };
  auto hwrite = [&](int pofs) {
#pragma unroll
    for (int c = 0; c < 8; ++c) {
      int cl = cg * 8 + c;
      float bia = prm[pofs + cl], gg = prm[pofs + 64 + cl], bb = prm[pofs + 128 + cl];
      unsigned int* hc = &xpk[(cb * 68 + cl) * XS + rg * 4];
#pragma unroll
      for (int i = 0; i < 4; ++i) {
        float za = getacc(2 * i, c) + bia;
        za = za > 0.f ? za : 0.f;
        za = za * gg + bb;
        float zb = getacc(2 * i + 1, c) + bia;
        zb = zb > 0.f ? zb : 0.f;
        zb = zb * gg + bb;
        hc[i] = packbf(za, zb);
      }
    }
  };
  __syncthreads();
#pragma unroll
  for (int i = 0; i < 32; ++i) acc2[i] = (v2f){0.f, 0.f};
  kloop(67);
  __syncthreads();
  hwrite(0);
  for (int i = tid; i < 64 * 64; i += 256) wbuf[i] = W1[i];
  __syncthreads();
#pragma unroll
  for (int i = 0; i < 32; ++i) acc2[i] = (v2f){0.f, 0.f};
  kloop(64);
  __syncthreads();
  hwrite(192);
  for (int i = tid; i < 64 * 64; i += 256) wbuf[i] = W2[(i >> 6) * C3 + (i & 63)];
  __syncthreads();
  float* outp = out_feat + (size_t)(bc * NP + sc) * C3;
#pragma unroll 1
  for (int half = 0; half < 2; ++half) {
    if (half) {
      __syncthreads();
      for (int i = tid; i < 64 * 64; i += 256)
        wbuf[i] = W2[(i >> 6) * C3 + 64 + (i & 63)];
      __syncthreads();
    }
#pragma unroll
    for (int i = 0; i < 32; ++i) acc2[i] = (v2f){0.f, 0.f};
    kloop(64);
    float vout[8];
#pragma unroll
    for (int c = 0; c < 8; ++c) {
      int cl = half * 64 + cg * 8 + c;
      float bia = prm[384 + cl], gg = prm[512 + cl], bb = prm[640 + cl];
      float mmax = -3.4e38f;
#pragma unroll
      for (int r = 0; r < 8; ++r) {
        float z = getacc(r, c) + bia;
        z = z > 0.f ? z : 0.f;
        z = z * gg + bb;
        mmax = fmaxf(mmax, z);
      }
      mmax = fmaxf(mmax, __shfl_xor(mmax, 8, 64));
      mmax = fmaxf(mmax, __shfl_xor(mmax, 16, 64));
      vout[c] = mmax;
    }
    if (rg == 0) {
      *(float4*)(outp + half * 64 + cg * 8) =
          make_float4(vout[0], vout[1], vout[2], vout[3]);
      *(float4*)(outp + half * 64 + cg * 8 + 4) =
          make_float4(vout[4], vout[5], vout[6], vout[7]);
    }
  }
}

extern "C" void kernel_launch(void* const* d_in, const int* in_sizes, int n_in,
                              void* d_out, int out_size, void* d_ws, size_t ws_size,
                              hipStream_t stream) {
  const float* xyz = (const float*)d_in[0];
  const float* points = (const float*)d_in[1];
  const float* W0 = (const float*)d_in[2];
  const float* b0 = (const float*)d_in[3];
  const float* g0 = (const float*)d_in[4];
  const float* be0 = (const float*)d_in[5];
  const float* W1 = (const float*)d_in[6];
  const float* b1 = (const float*)d_in[7];
  const float* g1 = (const float*)d_in[8];
  const float* be1 = (const float*)d_in[9];
  const float* W2 = (const float*)d_in[10];
  const float* b2 = (const float*)d_in[11];
  const float* g2 = (const float*)d_in[12];
  const float* be2 = (const float*)d_in[13];
  float* out = (float*)d_out;
  unsigned short* fps = (unsigned short*)d_ws;                    // 16 KB
  unsigned short* gidx = fps + (size_t)NB * NP;                   // 512 KB
  unsigned int* sent = (unsigned int*)((char*)d_ws + (16 + 512) * 1024);
  // Keep the explicit re-arm (measured-neutral, makes state explicit).
  hipMemsetAsync(sent, 0, NB * sizeof(unsigned int), stream);
  fps_kernel<<<GRID1, 1024, 0, stream>>>(xyz, fps, out, sent);
  ballq_kernel<<<(NB * NP) / 4, 256, 0, stream>>>(xyz, fps, gidx);
  mlp_kernel<<<NB * NP / 8, 256, 0, stream>>>(xyz, points, fps, gidx,
                                              W0, b0, g0, be0, W1, b1, g1, be1,
                                              W2, b2, g2, be2,
                                              out + (size_t)NB * NP * 3);
}

// Round 11
// 852.944 us; speedup vs baseline: 1.0461x; 1.0461x over previous
//
#include <hip/hip_runtime.h>
#include <stdint.h>

#define NB 8
#define NN 4096
#define NP 1024
#define NSAMP 32
#define CIN 64
#define C3 128
#define XS 20
#define SENT_DONE 0x00C0FFEEu
#define GRID1 8

typedef float v2f __attribute__((ext_vector_type(2)));

__device__ __forceinline__ float lo2f(unsigned int u) { return __uint_as_float(u << 16); }
__device__ __forceinline__ float hi2f(unsigned int u) { return __uint_as_float(u & 0xffff0000u); }
__device__ __forceinline__ unsigned short f2b(float f) {
  unsigned int u = __float_as_uint(f);
  unsigned int r = u + 0x7fffu + ((u >> 16) & 1u);
  return (unsigned short)(r >> 16);
}
__device__ __forceinline__ unsigned int packbf(float a, float b) {
  return (unsigned int)f2b(a) | ((unsigned int)f2b(b) << 16);
}

#define FMAXD(v, ctrl)                                                     \
  do {                                                                     \
    int _x = __float_as_int(v);                                            \
    int _m = __builtin_amdgcn_update_dpp(_x, _x, (ctrl), 0xf, 0xf, false); \
    (v) = fmaxf((v), __int_as_float(_m));                                  \
  } while (0)

// ---- Kernel 1: FPS ---------------------------------------------------------
// Waves 0-3: FPS at setprio(3); waves 4-15: co-resident pk-FMA ballast at
// setprio(0) -> per-CU DVFS boost (R19/R20 wins, per-CU issue-busy ~91%).
// Publish path: readlane(gi,wl) + lane==0 store (R22 proved lane==wl predicate
// REGRESSES +9.5us: v_cmp+exec-mask on publish path > readlane cost).
// R23: poll tag check AND-folded: ((s0&s1&s2&s3)>>44)==k is exactly
// equivalent (stale k' in {0, k-2}; AND(k,v)==k needs k<=v<k, impossible;
// idx bits shift out; k<1024 keeps bits 22+ zero) — ~7 fewer VALU per spin.
__global__ __launch_bounds__(1024, 1) void fps_kernel(
    const float* __restrict__ xyz, unsigned short* __restrict__ fps_g,
    float* __restrict__ out_xyz, unsigned int* __restrict__ sent) {
#pragma clang fp contract(off)
  const int tid = threadIdx.x;
  const int b = blockIdx.x;
  const int lane = tid & 63;
  const int wv = tid >> 6;  // 0..15
  __shared__ float sx[NN], sy[NN], sz[NN];
  __shared__ __align__(16) unsigned long long slotmem[2][4];
  __shared__ unsigned short scidx[NP];
  __shared__ unsigned int sdone;
  const float* xb = xyz + (size_t)b * NN * 3;
  if (wv < 4) {
    for (int i = tid; i < NN; i += 256) {
      sx[i] = xb[3 * i + 0];
      sy[i] = xb[3 * i + 1];
      sz[i] = xb[3 * i + 2];
    }
    if (tid < 8) ((unsigned long long*)slotmem)[tid] = 0ull;  // k-field 0
    if (tid == 0) { scidx[0] = 0; sdone = 0u; }
  }
  __syncthreads();
  if (wv >= 4) {
    // ---- co-resident ballast: register-only pk-FMA, rare LDS flag check
#if __has_builtin(__builtin_amdgcn_s_setprio)
    __builtin_amdgcn_s_setprio(0);
#endif
    v2f a[8];
#pragma unroll
    for (int i = 0; i < 8; ++i) {
      float base = 1.0f + (float)(tid & 15) * 1e-6f + (float)i * 1e-7f;
      a[i] = (v2f){base, base + 1e-7f};
    }
    const v2f c1 = (v2f){1.0000001f, 1.0000001f};
    const v2f c2 = (v2f){1e-9f, 1e-9f};
    for (int r = 0; r < 400000; ++r) {
#pragma unroll
      for (int i = 0; i < 8; ++i) a[i] = a[i] * c1 + c2;
      if ((r & 63) == 0) {
        if (__hip_atomic_load(&sdone, __ATOMIC_RELAXED,
                              __HIP_MEMORY_SCOPE_WORKGROUP) != 0u)
          break;
      }
    }
    float s = 0.f;
#pragma unroll
    for (int i = 0; i < 8; ++i) s += a[i].x + a[i].y;
    asm volatile("" ::"v"(s));  // keep ballast live (rule #17)
  } else {
    // ---- FPS path
#if __has_builtin(__builtin_amdgcn_s_setprio)
    __builtin_amdgcn_s_setprio(3);
#endif
    v2f px[8], py[8], pz[8], dd[8];
#pragma unroll
    for (int i = 0; i < 8; ++i) {
      int i0 = tid * 16 + 2 * i;
      px[i] = (v2f){sx[i0], sx[i0 + 1]};
      py[i] = (v2f){sy[i0], sy[i0 + 1]};
      pz[i] = (v2f){sz[i0], sz[i0 + 1]};
      dd[i] = (v2f){1e10f, 1e10f};
    }
    float qx = sx[0], qy = sy[0], qz = sz[0];
    for (int k = 1; k < NP; ++k) {
      v2f q2x = (v2f){qx, qx};
      v2f q2y = (v2f){qy, qy};
      v2f q2z = (v2f){qz, qz};
#pragma unroll
      for (int i = 0; i < 8; ++i) {
        v2f dx = px[i] - q2x;
        v2f dy = py[i] - q2y;
        v2f dz = pz[i] - q2z;
        v2f xx = dx * dx;
        v2f yy = dy * dy;
        v2f zz = dz * dz;
        v2f s = xx + yy;
        v2f d = s + zz;  // per-element np order, contract off
        dd[i] = __builtin_elementwise_min(dd[i], d);
      }
      // intra-thread argmax over 16 (first-index ties: strict >, left=lower)
      float v1[8]; int j1[8];
#pragma unroll
      for (int i = 0; i < 8; ++i) {
        bool g = dd[i].y > dd[i].x;
        v1[i] = g ? dd[i].y : dd[i].x;
        j1[i] = 2 * i + (g ? 1 : 0);
      }
      float v2a[4]; int j2a[4];
#pragma unroll
      for (int i = 0; i < 4; ++i) {
        bool g = v1[2 * i + 1] > v1[2 * i];
        v2a[i] = g ? v1[2 * i + 1] : v1[2 * i];
        j2a[i] = g ? j1[2 * i + 1] : j1[2 * i];
      }
      float v3[2]; int j3[2];
#pragma unroll
      for (int i = 0; i < 2; ++i) {
        bool g = v2a[2 * i + 1] > v2a[2 * i];
        v3[i] = g ? v2a[2 * i + 1] : v2a[2 * i];
        j3[i] = g ? j2a[2 * i + 1] : j2a[2 * i];
      }
      bool g0 = v3[1] > v3[0];
      float bestv = g0 ? v3[1] : v3[0];
      int gi = tid * 16 + (g0 ? j3[1] : j3[0]);
      // wave max via DPP
      float m = bestv;
      FMAXD(m, 0x111); FMAXD(m, 0x112); FMAXD(m, 0x114);
      FMAXD(m, 0x118); FMAXD(m, 0x142); FMAXD(m, 0x143);
      float wmax =
          __int_as_float(__builtin_amdgcn_readlane(__float_as_int(m), 63));
      unsigned long long ball = __ballot(bestv == wmax);
      int wl = __ffsll((long long)ball) - 1;  // lowest lane == lowest index
      int widx = __builtin_amdgcn_readlane(gi, wl);
      unsigned long long rec =
          ((unsigned long long)(((unsigned)k << 12) | (unsigned)widx) << 32) |
          (unsigned long long)__float_as_uint(wmax);
      unsigned long long* sl = &slotmem[k & 1][0];
      if (lane == 0) sl[wv] = rec;
      asm volatile("" ::: "memory");
      // poll: two independent 16B loads per spin; AND-folded tag check (R23)
      unsigned long long s0, s1, s2, s3;
      for (;;) {
        ulonglong2 pa = *(const ulonglong2*)(sl);
        ulonglong2 pb = *(const ulonglong2*)(sl + 2);
        s0 = pa.x; s1 = pa.y; s2 = pb.x; s3 = pb.y;
        if ((unsigned)((s0 & s1 & s2 & s3) >> 44) == (unsigned)k) break;
        asm volatile("" ::: "memory");
      }
      float bv = __uint_as_float((unsigned)s0);
      int wi = (int)((s0 >> 32) & 0xFFFu);
      {
        float v = __uint_as_float((unsigned)s1);
        int iw = (int)((s1 >> 32) & 0xFFFu);
        bool g = v > bv; bv = g ? v : bv; wi = g ? iw : wi;
      }
      {
        float v = __uint_as_float((unsigned)s2);
        int iw = (int)((s2 >> 32) & 0xFFFu);
        bool g = v > bv; bv = g ? v : bv; wi = g ? iw : wi;
      }
      {
        float v = __uint_as_float((unsigned)s3);
        int iw = (int)((s3 >> 32) & 0xFFFu);
        bool g = v > bv; bv = g ? v : bv; wi = g ? iw : wi;
      }
      qx = sx[wi]; qy = sy[wi]; qz = sz[wi];  // broadcast reads
      if (tid == 0) scidx[k] = (unsigned short)wi;
    }
    if (tid == 0)
      __hip_atomic_store(&sdone, 1u, __ATOMIC_RELAXED,
                         __HIP_MEMORY_SCOPE_WORKGROUP);
  }
  __syncthreads();
  for (int i = tid; i < NP; i += 1024) {
    int id = scidx[i];
    out_xyz[((size_t)b * NP + i) * 3 + 0] = sx[id];
    out_xyz[((size_t)b * NP + i) * 3 + 1] = sy[id];
    out_xyz[((size_t)b * NP + i) * 3 + 2] = sz[id];
    fps_g[b * NP + i] = (unsigned short)id;
  }
  __syncthreads();
  if (tid == 0)
    __hip_atomic_store(&sent[b], SENT_DONE, __ATOMIC_RELAXED,
                       __HIP_MEMORY_SCOPE_AGENT);
}

// ---- Kernel 2: ball query (one wave per center; standalone — R10) ----------
__global__ __launch_bounds__(256) void ballq_kernel(
    const float* __restrict__ xyz, const unsigned short* __restrict__ fps_idx,
    unsigned short* __restrict__ gidx) {
#pragma clang fp contract(off)
  const int tid = threadIdx.x;
  const int gid = blockIdx.x * 4 + (tid >> 6);
  const int lane = tid & 63;
  const int b = gid >> 10;
  const int s = gid & 1023;
  const float* xb = xyz + (size_t)b * NN * 3;
  const int ci = (int)fps_idx[b * NP + s] & (NN - 1);
  const float cx = xb[ci * 3 + 0];
  const float cy = xb[ci * 3 + 1];
  const float cz = xb[ci * 3 + 2];
  const float nn = (cx * cx + cy * cy) + cz * cz;
  const float r2 = 0.04f;
  unsigned short* gout = gidx + (size_t)(b * NP + s) * NSAMP;
  int total = 0;
  int first = -1;
  for (int c = 0; c < NN / 64 && total < NSAMP; ++c) {
    int i = (c << 6) + lane;
    float x = xb[i * 3 + 0];
    float y = xb[i * 3 + 1];
    float z = xb[i * 3 + 2];
    float pp = (x * x + y * y) + z * z;
    float dt = (x * cx + y * cy) + z * cz;
    float sq = (nn + pp) - 2.0f * dt;  // exact ref formula; self-dist == 0
    bool inb = !(sq > r2);
    unsigned long long m = __ballot(inb);
    if (first < 0 && m) first = (c << 6) + (__ffsll((unsigned long long)m) - 1);
    int before = __popcll(m & ((1ull << lane) - 1ull));
    int slot = total + before;
    if (inb && slot < NSAMP) gout[slot] = (unsigned short)i;
    total += (int)__popcll(m);
  }
  int cnt = total < NSAMP ? total : NSAMP;
  unsigned short fill = (unsigned short)(first < 0 ? 0 : first);
  if (lane >= cnt && lane < NSAMP) gout[lane] = fill;
}

// ---- Kernel 3: gather + MLP(67->64->64->128) + max --------------------------
// R21: v2f accumulator + elementwise_fma (v_pk_fma_f32). Measured neutral vs
// scalar (compiler SLP had it covered) — kept, bit-identical math.
__global__ __launch_bounds__(256) void mlp_kernel(
    const float* __restrict__ xyz, const float* __restrict__ points,
    const unsigned short* __restrict__ fps_idx, const unsigned short* __restrict__ gidx,
    const float* __restrict__ W0, const float* __restrict__ b0,
    const float* __restrict__ g0, const float* __restrict__ be0,
    const float* __restrict__ W1, const float* __restrict__ b1,
    const float* __restrict__ g1, const float* __restrict__ be1,
    const float* __restrict__ W2, const float* __restrict__ b2,
    const float* __restrict__ g2, const float* __restrict__ be2,
    float* __restrict__ out_feat) {
  __shared__ __align__(16) float wbuf[4352];
  __shared__ __align__(16) unsigned int xpk[8 * 68 * XS];
  __shared__ float prm[768];
  const int tid = threadIdx.x;
  const float bnsc = 1.0f / sqrtf(1.001f);
  if (tid < 64) {
    prm[tid] = b0[tid];       prm[64 + tid] = g0[tid] * bnsc;  prm[128 + tid] = be0[tid];
    prm[192 + tid] = b1[tid]; prm[256 + tid] = g1[tid] * bnsc; prm[320 + tid] = be1[tid];
  }
  if (tid < 128) {
    prm[384 + tid] = b2[tid]; prm[512 + tid] = g2[tid] * bnsc; prm[640 + tid] = be2[tid];
  }
  if (tid < 128) {
    const int cbg = tid >> 4, r2 = tid & 15;
    const int sgg = blockIdx.x * 8 + cbg;
    const int bg = sgg >> 10, sg = sgg & 1023;
    const unsigned short* gi = gidx + (size_t)(bg * NP + sg) * NSAMP;
    const int i0 = (int)gi[2 * r2] & (NN - 1);
    const int i1 = (int)gi[2 * r2 + 1] & (NN - 1);
    const int ci = (int)fps_idx[bg * NP + sg] & (NN - 1);
    const float* xb = xyz + (size_t)bg * NN * 3;
    unsigned int* xc = &xpk[(cbg * 68) * XS + r2];
    const float cx = xb[ci * 3], cy = xb[ci * 3 + 1], cz = xb[ci * 3 + 2];
    xc[0 * XS] = packbf(xb[i0 * 3] - cx,     xb[i1 * 3] - cx);
    xc[1 * XS] = packbf(xb[i0 * 3 + 1] - cy, xb[i1 * 3 + 1] - cy);
    xc[2 * XS] = packbf(xb[i0 * 3 + 2] - cz, xb[i1 * 3 + 2] - cz);
    const float4* p0 = (const float4*)(points + ((size_t)bg * NN + i0) * CIN);
    const float4* p1 = (const float4*)(points + ((size_t)bg * NN + i1) * CIN);
#pragma unroll 4
    for (int kk = 0; kk < 16; ++kk) {
      float4 a = p0[kk], c = p1[kk];
      xc[(3 + 4 * kk) * XS] = packbf(a.x, c.x);
      xc[(4 + 4 * kk) * XS] = packbf(a.y, c.y);
      xc[(5 + 4 * kk) * XS] = packbf(a.z, c.z);
      xc[(6 + 4 * kk) * XS] = packbf(a.w, c.w);
    }
  } else {
    for (int i = tid - 128; i < 67 * 64; i += 128) wbuf[i] = W0[i];
  }
  const int cb = tid >> 5, rg = (tid >> 3) & 3, cg = tid & 7;
  const int sgc = blockIdx.x * 8 + cb;
  const int bc = sgc >> 10, sc = sgc & 1023;
  const unsigned int* xrow = &xpk[(cb * 68) * XS + rg * 4];
  // acc[r*8+c] == acc2[r*4 + (c>>1)] component (c&1)
  v2f acc2[32];
  auto getacc = [&](int r, int c) -> float {
    v2f t = acc2[r * 4 + (c >> 1)];
    return (c & 1) ? t.y : t.x;
  };
  auto kloop = [&](int K) {
    uint4 xp = *(const uint4*)(xrow);
    float4 wa = *(const float4*)&wbuf[cg * 8];
    float4 wc = *(const float4*)&wbuf[cg * 8 + 4];
#pragma unroll 2
    for (int k = 0; k < K; ++k) {
      uint4 xpn = *(const uint4*)(xrow + (k + 1) * XS);
      float4 wan = *(const float4*)&wbuf[(k + 1) * 64 + cg * 8];
      float4 wcn = *(const float4*)&wbuf[(k + 1) * 64 + cg * 8 + 4];
      float xr[8] = {lo2f(xp.x), hi2f(xp.x), lo2f(xp.y), hi2f(xp.y),
                     lo2f(xp.z), hi2f(xp.z), lo2f(xp.w), hi2f(xp.w)};
      v2f w01 = (v2f){wa.x, wa.y};
      v2f w23 = (v2f){wa.z, wa.w};
      v2f w45 = (v2f){wc.x, wc.y};
      v2f w67 = (v2f){wc.z, wc.w};
#pragma unroll
      for (int r = 0; r < 8; ++r) {
        v2f xq = (v2f){xr[r], xr[r]};
        acc2[r * 4 + 0] = __builtin_elementwise_fma(xq, w01, acc2[r * 4 + 0]);
        acc2[r * 4 + 1] = __builtin_elementwise_fma(xq, w23, acc2[r * 4 + 1]);
        acc2[r * 4 + 2] = __builtin_elementwise_fma(xq, w45, acc2[r * 4 + 2]);
        acc2[r * 4 + 3] = __builtin_elementwise_fma(xq, w67, acc2[r * 4 + 3]);
      }
      xp = xpn; wa = wan; wc = wcn;
    }
  };
  auto hwrite = [&](int pofs) {
#pragma unroll
    for (int c = 0; c < 8; ++c) {
      int cl = cg * 8 + c;
      float bia = prm[pofs + cl], gg = prm[pofs + 64 + cl], bb = prm[pofs + 128 + cl];
      unsigned int* hc = &xpk[(cb * 68 + cl) * XS + rg * 4];
#pragma unroll
      for (int i = 0; i < 4; ++i) {
        float za = getacc(2 * i, c) + bia;
        za = za > 0.f ? za : 0.f;
        za = za * gg + bb;
        float zb = getacc(2 * i + 1, c) + bia;
        zb = zb > 0.f ? zb : 0.f;
        zb = zb * gg + bb;
        hc[i] = packbf(za, zb);
      }
    }
  };
  __syncthreads();
#pragma unroll
  for (int i = 0; i < 32; ++i) acc2[i] = (v2f){0.f, 0.f};
  kloop(67);
  __syncthreads();
  hwrite(0);
  for (int i = tid; i < 64 * 64; i += 256) wbuf[i] = W1[i];
  __syncthreads();
#pragma unroll
  for (int i = 0; i < 32; ++i) acc2[i] = (v2f){0.f, 0.f};
  kloop(64);
  __syncthreads();
  hwrite(192);
  for (int i = tid; i < 64 * 64; i += 256) wbuf[i] = W2[(i >> 6) * C3 + (i & 63)];
  __syncthreads();
  float* outp = out_feat + (size_t)(bc * NP + sc) * C3;
#pragma unroll 1
  for (int half = 0; half < 2; ++half) {
    if (half) {
      __syncthreads();
      for (int i = tid; i < 64 * 64; i += 256)
        wbuf[i] = W2[(i >> 6) * C3 + 64 + (i & 63)];
      __syncthreads();
    }
#pragma unroll
    for (int i = 0; i < 32; ++i) acc2[i] = (v2f){0.f, 0.f};
    kloop(64);
    float vout[8];
#pragma unroll
    for (int c = 0; c < 8; ++c) {
      int cl = half * 64 + cg * 8 + c;
      float bia = prm[384 + cl], gg = prm[512 + cl], bb = prm[640 + cl];
      float mmax = -3.4e38f;
#pragma unroll
      for (int r = 0; r < 8; ++r) {
        float z = getacc(r, c) + bia;
        z = z > 0.f ? z : 0.f;
        z = z * gg + bb;
        mmax = fmaxf(mmax, z);
      }
      mmax = fmaxf(mmax, __shfl_xor(mmax, 8, 64));
      mmax = fmaxf(mmax, __shfl_xor(mmax, 16, 64));
      vout[c] = mmax;
    }
    if (rg == 0) {
      *(float4*)(outp + half * 64 + cg * 8) =
          make_float4(vout[0], vout[1], vout[2], vout[3]);
      *(float4*)(outp + half * 64 + cg * 8 + 4) =
          make_float4(vout[4], vout[5], vout[6], vout[7]);
    }
  }
}

extern "C" void kernel_launch(void* const* d_in, const int* in_sizes, int n_in,
                              void* d_out, int out_size, void* d_ws, size_t ws_size,
                              hipStream_t stream) {
  const float* xyz = (const float*)d_in[0];
  const float* points = (const float*)d_in[1];
  const float* W0 = (const float*)d_in[2];
  const float* b0 = (const float*)d_in[3];
  const float* g0 = (const float*)d_in[4];
  const float* be0 = (const float*)d_in[5];
  const float* W1 = (const float*)d_in[6];
  const float* b1 = (const float*)d_in[7];
  const float* g1 = (const float*)d_in[8];
  const float* be1 = (const float*)d_in[9];
  const float* W2 = (const float*)d_in[10];
  const float* b2 = (const float*)d_in[11];
  const float* g2 = (const float*)d_in[12];
  const float* be2 = (const float*)d_in[13];
  float* out = (float*)d_out;
  unsigned short* fps = (unsigned short*)d_ws;                    // 16 KB
  unsigned short* gidx = fps + (size_t)NB * NP;                   // 512 KB
  unsigned int* sent = (unsigned int*)((char*)d_ws + (16 + 512) * 1024);
  // Keep the explicit re-arm (measured-neutral, makes state explicit).
  hipMemsetAsync(sent, 0, NB * sizeof(unsigned int), stream);
  fps_kernel<<<GRID1, 1024, 0, stream>>>(xyz, fps, out, sent);
  ballq_kernel<<<(NB * NP) / 4, 256, 0, stream>>>(xyz, fps, gidx);
  mlp_kernel<<<NB * NP / 8, 256, 0, stream>>>(xyz, points, fps, gidx,
                                              W0, b0, g0, be0, W1, b1, g1, be1,
                                              W2, b2, g2, be2,
                                              out + (size_t)NB * NP * 3);
}